// Round 10
// baseline (170.819 us; speedup 1.0000x reference)
//
#include <hip/hip_runtime.h>

#define NM    4096
#define NPTS  131072
#define CAP   128

typedef _Float16 h8 __attribute__((ext_vector_type(8)));
typedef _Float16 h2 __attribute__((ext_vector_type(2)));
typedef float    f4 __attribute__((ext_vector_type(4)));
typedef int      i4 __attribute__((ext_vector_type(4)));
// 4B-aligned float4 for odd-stride rows (w0:63, vw:59); AMDGPU emits
// dword-aligned dwordx4 (or splits) — correct either way.
typedef float    f4u __attribute__((ext_vector_type(4), aligned(4)));

#define MF(a, b, c) __builtin_amdgcn_mfma_f32_16x16x32_f16((a), (b), (c), 0, 0, 0)

static __device__ inline h2 pk(float a, float b) {
    return __builtin_bit_cast(h2, __builtin_amdgcn_cvt_pkrtz(a, b));
}

static __device__ inline h8 pack8(float u0, float u1, float u2, float u3,
                                  float u4, float u5, float u6, float u7) {
    i4 t;
    t[0] = __builtin_bit_cast(int, pk(u0, u1));
    t[1] = __builtin_bit_cast(int, pk(u2, u3));
    t[2] = __builtin_bit_cast(int, pk(u4, u5));
    t[3] = __builtin_bit_cast(int, pk(u6, u7));
    return __builtin_bit_cast(h8, t);
}

// NeRF frequency-encoding dim d of (x,y,z); 0 for d >= lim.
static __device__ inline float encdim(int d, int lim, float x, float y, float z) {
    int tt = d - 3;
    int k  = tt / 6;
    int r  = tt - 6 * k;
    float p = x;
    p = (r == 1 || r == 4) ? y : p;
    p = (r == 2 || r == 5) ? z : p;
    float f   = __int_as_float((k + 127) << 23);   // 2^k
    float arg = p * f + ((r >= 3) ? 1.57079632679f : 0.f);  // cos = sin(+pi/2)
    float sv  = __sinf(arg);
    float raw = (d == 0) ? x : ((d == 1) ? y : z);
    float val = (d < 3) ? raw : sv;
    return (d < lim) ? val : 0.f;
}

// D-frag pair -> B-frag (verified lineage; R14's d1[0] typo fixed in R15).
static __device__ inline h8 makeB(f4 d0, f4 d1, int quad, int col) {
    int laneA = ((quad & 1) * 2) * 16 + col;
    int laneB = laneA + 16;
    float a0 = __shfl(d0[0], laneA), b0 = __shfl(d1[0], laneA);
    float a1 = __shfl(d0[1], laneA), b1 = __shfl(d1[1], laneA);
    float a2 = __shfl(d0[2], laneA), b2 = __shfl(d1[2], laneA);
    float a3 = __shfl(d0[3], laneA), b3 = __shfl(d1[3], laneA);
    float a4 = __shfl(d0[0], laneB), b4 = __shfl(d1[0], laneB);
    float a5 = __shfl(d0[1], laneB), b5 = __shfl(d1[1], laneB);
    float a6 = __shfl(d0[2], laneB), b6 = __shfl(d1[2], laneB);
    float a7 = __shfl(d0[3], laneB), b7 = __shfl(d1[3], laneB);
    bool hi = quad >= 2;
    return pack8(hi ? b0 : a0, hi ? b1 : a1, hi ? b2 : a2, hi ? b3 : a3,
                 hi ? b4 : a4, hi ? b5 : a5, hi ? b6 : a6, hi ? b7 : a7);
}

static __device__ inline f4 relu4(f4 a) {
    f4 r;
    r[0] = fmaxf(a[0], 0.f); r[1] = fmaxf(a[1], 0.f);
    r[2] = fmaxf(a[2], 0.f); r[3] = fmaxf(a[3], 0.f);
    return r;
}

__global__ __launch_bounds__(256) void k_bucket(const float* __restrict__ pts,
                                                int* __restrict__ count,
                                                int* __restrict__ plist) {
    int n = blockIdx.x * 256 + threadIdx.x;
    if (n >= NPTS) return;
    float x = pts[3 * n + 0], y = pts[3 * n + 1], z = pts[3 * n + 2];
    int ix = (int)fminf(fmaxf(x * 16.f, 0.f), 15.f);
    int iy = (int)fminf(fmaxf(y * 16.f, 0.f), 15.f);
    int iz = (int)fminf(fmaxf(z * 16.f, 0.f), 15.f);
    int v = (ix << 8) | (iy << 4) | iz;
    int pos = atomicAdd(&count[v], 1);
    if (pos < CAP) plist[v * CAP + pos] = n;
}

// R18: ZERO-LDS — direct-to-register fragment loads.
// R17 measured per-voxel wall 2.6us vs ~1.2us of issue work at 1 wave/SIMD
// (VALUBusy 16%): dependency-chain stalls with no co-resident waves to hide
// them. Every prior design carried 12-48KB LDS -> 4-6 blocks/CU cap. Here
// fragments load straight from global into VGPRs (2 x dwordx4 per h8 frag,
// lim-selects zero the tail, cvt_pkrtz as before); no LDS, no DMA, no
// barriers, no inline waits — compiler emits counted per-operand waits.
// LDS=0 + __launch_bounds__(64,3) (VGPR<=170) -> 12 blocks/CU residency.
// OOB edges: odd-stride rows read <=5 elems into the NEXT row (finite
// weight garbage, select-zeroed -> no NaN); the single globally-last row
// (v=4095,Ti=1,col=15,quad=3) would read past the allocation -> that one
// lane uses a scalar clamped path.
__global__ __launch_bounds__(64, 3) void k_mlp(
    const float* __restrict__ pts, const float* __restrict__ vds,
    const float* __restrict__ w0g, const float* __restrict__ b0g,
    const float* __restrict__ w1g, const float* __restrict__ b1g,
    const float* __restrict__ fwg, const float* __restrict__ fbg,
    const float* __restrict__ swg, const float* __restrict__ sbg,
    const float* __restrict__ vwg, const float* __restrict__ vbg,
    const float* __restrict__ rwg, const float* __restrict__ rbg,
    const int* __restrict__ count, const int* __restrict__ plist,
    float* __restrict__ out) {
    const int lane = threadIdx.x & 63;
    const int col  = lane & 15;
    const int quad = lane >> 4;
    const int k8   = quad * 8;
    const int v    = blockIdx.x;
    const int c    = min(count[v], CAP);
    if (c == 0) return;

    // ---- whole plist row via 2 coalesced loads + shfl broadcast (R16) ----
    const int prow0 = plist[v * CAP + lane];
    const int prow1 = plist[v * CAP + 64 + lane];
    auto chunk_idx = [&](int base) -> int {
        int e = min(base + col, c - 1);
        int a = __shfl(prow0, e);
        int b = __shfl(prow1, e - 64);
        return (e < 64) ? a : b;
    };

    // ---- direct fragment loads ----
    h8 aW0[2][2], aW1[2], aVW[2][2], aFW[2], aSG, aRGB;
    const bool q3 = (k8 == 24);
    #pragma unroll
    for (int Ti = 0; Ti < 2; Ti++) {
        const bool rare = (v == NM - 1) && (Ti == 1) && (col == 15) && q3;

        // w0: rows of 63 (d-lim 63). frag0 d=k8..k8+7 (<32+8<=31<63: no select).
        const float* r0 = w0g + (size_t)v * 2016 + (Ti * 16 + col) * 63;
        {
            f4u a = *(const f4u*)(r0 + k8);
            f4u b = *(const f4u*)(r0 + k8 + 4);
            aW0[Ti][0] = pack8(a[0], a[1], a[2], a[3], b[0], b[1], b[2], b[3]);
        }
        if (rare) {
            float u[8];
            #pragma unroll
            for (int j = 0; j < 8; j++) {
                int d = 32 + k8 + j;
                u[j] = (d < 63) ? r0[min(d, 62)] : 0.f;
            }
            aW0[Ti][1] = pack8(u[0], u[1], u[2], u[3], u[4], u[5], u[6], u[7]);
        } else {
            f4u a = *(const f4u*)(r0 + 32 + k8);
            f4u b = *(const f4u*)(r0 + 36 + k8);
            float u7 = q3 ? 0.f : b[3];            // d=63 -> 0
            aW0[Ti][1] = pack8(a[0], a[1], a[2], a[3], b[0], b[1], b[2], u7);
        }

        // vw: rows of 59 (d-lim 59). frag0 d<=31<59: no select.
        const float* r1 = vwg + (size_t)v * 1888 + (Ti * 16 + col) * 59;
        {
            f4u a = *(const f4u*)(r1 + k8);
            f4u b = *(const f4u*)(r1 + k8 + 4);
            aVW[Ti][0] = pack8(a[0], a[1], a[2], a[3], b[0], b[1], b[2], b[3]);
        }
        if (rare) {
            float u[8];
            #pragma unroll
            for (int j = 0; j < 8; j++) {
                int d = 32 + k8 + j;
                u[j] = (d < 59) ? r1[min(d, 58)] : 0.f;
            }
            aVW[Ti][1] = pack8(u[0], u[1], u[2], u[3], u[4], u[5], u[6], u[7]);
        } else {
            f4u a = *(const f4u*)(r1 + 32 + k8);
            f4u b = *(const f4u*)(r1 + 36 + k8);
            float u3 = q3 ? 0.f : a[3];            // quad3: d=59..63 -> 0
            float u4 = q3 ? 0.f : b[0];
            float u5 = q3 ? 0.f : b[1];
            float u6 = q3 ? 0.f : b[2];
            float u7 = q3 ? 0.f : b[3];
            aVW[Ti][1] = pack8(a[0], a[1], a[2], u3, u4, u5, u6, u7);
        }

        // w1/fw: aligned 32-float rows, no selects.
        {
            const float* r2 = w1g + (size_t)v * 1024 + (Ti * 16 + col) * 32 + k8;
            f4 a = *(const f4*)r2;
            f4 b = *(const f4*)(r2 + 4);
            aW1[Ti] = pack8(a[0], a[1], a[2], a[3], b[0], b[1], b[2], b[3]);
        }
        {
            const float* r3 = fwg + (size_t)v * 1024 + (Ti * 16 + col) * 32 + k8;
            f4 a = *(const f4*)r3;
            f4 b = *(const f4*)(r3 + 4);
            aFW[Ti] = pack8(a[0], a[1], a[2], a[3], b[0], b[1], b[2], b[3]);
        }
    }
    {
        const float* rs = swg + (size_t)v * 32 + k8;   // broadcast row 0
        f4 a = *(const f4*)rs;
        f4 b = *(const f4*)(rs + 4);
        aSG = (col == 0) ? pack8(a[0], a[1], a[2], a[3], b[0], b[1], b[2], b[3]) : h8{};
    }
    {
        int cc = min(col, 2);                          // clamp keeps addr in-bounds
        const float* rr = rwg + (size_t)v * 96 + cc * 32 + k8;
        f4 a = *(const f4*)rr;
        f4 b = *(const f4*)(rr + 4);
        aRGB = (col < 3) ? pack8(a[0], a[1], a[2], a[3], b[0], b[1], b[2], b[3]) : h8{};
    }

    // ---- biases (aligned f4 rows) ----
    f4 cB0[2], cB1[2], cFB[2], cVB[2];
    #pragma unroll
    for (int Ti = 0; Ti < 2; Ti++) {
        int ro = v * 32 + Ti * 16 + quad * 4;
        cB0[Ti] = *(const f4*)(b0g + ro);
        cB1[Ti] = *(const f4*)(b1g + ro);
        cFB[Ti] = *(const f4*)(fbg + ro);
        cVB[Ti] = *(const f4*)(vbg + ro);
    }
    const float rb0 = rbg[v * 3 + 0], rb1 = rbg[v * 3 + 1], rb2 = rbg[v * 3 + 2];
    const float sb  = sbg[v];

    const f4 z4 = {0.f, 0.f, 0.f, 0.f};
    h8 bE0, bE1, bD;
    auto encode = [&](float sx, float sy, float sz, float tx, float ty, float tz) {
        bE0 = pack8(encdim(k8 + 0, 63, sx, sy, sz), encdim(k8 + 1, 63, sx, sy, sz),
                    encdim(k8 + 2, 63, sx, sy, sz), encdim(k8 + 3, 63, sx, sy, sz),
                    encdim(k8 + 4, 63, sx, sy, sz), encdim(k8 + 5, 63, sx, sy, sz),
                    encdim(k8 + 6, 63, sx, sy, sz), encdim(k8 + 7, 63, sx, sy, sz));
        bE1 = pack8(encdim(32 + k8 + 0, 63, sx, sy, sz), encdim(32 + k8 + 1, 63, sx, sy, sz),
                    encdim(32 + k8 + 2, 63, sx, sy, sz), encdim(32 + k8 + 3, 63, sx, sy, sz),
                    encdim(32 + k8 + 4, 63, sx, sy, sz), encdim(32 + k8 + 5, 63, sx, sy, sz),
                    encdim(32 + k8 + 6, 63, sx, sy, sz), encdim(32 + k8 + 7, 63, sx, sy, sz));
        bD  = pack8(encdim(k8 + 0, 27, tx, ty, tz), encdim(k8 + 1, 27, tx, ty, tz),
                    encdim(k8 + 2, 27, tx, ty, tz), encdim(k8 + 3, 27, tx, ty, tz),
                    encdim(k8 + 4, 27, tx, ty, tz), encdim(k8 + 5, 27, tx, ty, tz),
                    encdim(k8 + 6, 27, tx, ty, tz), encdim(k8 + 7, 27, tx, ty, tz));
    };

    auto do_chunk = [&](int n, bool active) {
        f4 d0 = MF(aW0[0][0], bE0, cB0[0]); d0 = MF(aW0[0][1], bE1, d0);
        f4 d1 = MF(aW0[1][0], bE0, cB0[1]); d1 = MF(aW0[1][1], bE1, d1);
        d0 = relu4(d0); d1 = relu4(d1);
        h8 bH = makeB(d0, d1, quad, col);
        f4 e0 = MF(aW1[0], bH, cB1[0]);
        f4 e1 = MF(aW1[1], bH, cB1[1]);
        e0 = relu4(e0); e1 = relu4(e1);
        h8 bG = makeB(e0, e1, quad, col);
        f4 s  = MF(aSG, bG, z4);
        f4 f0 = MF(aFW[0], bG, cFB[0]);
        f4 f1 = MF(aFW[1], bG, cFB[1]);
        h8 bF = makeB(f0, f1, quad, col);
        f4 v0 = MF(aVW[0][0], bF, cVB[0]); v0 = MF(aVW[0][1], bD, v0);
        f4 v1 = MF(aVW[1][0], bF, cVB[1]); v1 = MF(aVW[1][1], bD, v1);
        v0 = relu4(v0); v1 = relu4(v1);
        h8 bV = makeB(v0, v1, quad, col);
        f4 o  = MF(aRGB, bV, z4);
        if (quad == 0 && active) {
            out[3 * n + 0] = o[0] + rb0;
            out[3 * n + 1] = o[1] + rb1;
            out[3 * n + 2] = o[2] + rb2;
            out[3 * NPTS + n] = s[0] + sb;
        }
    };

    // ---- chunk 0 + chunk 1 prefetch ----
    int ncur = chunk_idx(0);
    float px = pts[3 * ncur], py = pts[3 * ncur + 1], pz = pts[3 * ncur + 2];
    int ray = ncur >> 7;
    float dx = vds[3 * ray], dy = vds[3 * ray + 1], dz = vds[3 * ray + 2];

    int nnxt = 0;
    float qx = 0.f, qy = 0.f, qz = 0.f, ex = 0.f, ey = 0.f, ez = 0.f;
    if (16 < c) {
        nnxt = chunk_idx(16);
        qx = pts[3 * nnxt]; qy = pts[3 * nnxt + 1]; qz = pts[3 * nnxt + 2];
        int r2 = nnxt >> 7;
        ex = vds[3 * r2]; ey = vds[3 * r2 + 1]; ez = vds[3 * r2 + 2];
    }

    encode(px, py, pz, dx, dy, dz);
    do_chunk(ncur, col < c);

    // ---- remaining chunks with next-chunk prefetch ----
    for (int base = 16; base < c; base += 16) {
        // snapshot prefetched data BEFORE issuing next prefetch (R10 lesson)
        const int n = nnxt;
        const float cx = qx, cy = qy, cz = qz;
        const float fx = ex, fy = ey, fz = ez;

        if (base + 16 < c) {
            nnxt = chunk_idx(base + 16);
            qx = pts[3 * nnxt]; qy = pts[3 * nnxt + 1]; qz = pts[3 * nnxt + 2];
            int r2 = nnxt >> 7;
            ex = vds[3 * r2]; ey = vds[3 * r2 + 1]; ez = vds[3 * r2 + 2];
        }

        encode(cx, cy, cz, fx, fy, fz);
        do_chunk(n, (base + col) < c);
    }
}

extern "C" void kernel_launch(void* const* d_in, const int* in_sizes, int n_in,
                              void* d_out, int out_size, void* d_ws, size_t ws_size,
                              hipStream_t stream) {
    const float* pts = (const float*)d_in[0];
    const float* vds = (const float*)d_in[1];
    const float* w0  = (const float*)d_in[2];
    const float* b0  = (const float*)d_in[3];
    const float* w1  = (const float*)d_in[4];
    const float* b1  = (const float*)d_in[5];
    const float* fw  = (const float*)d_in[6];
    const float* fb  = (const float*)d_in[7];
    const float* sw  = (const float*)d_in[8];
    const float* sb  = (const float*)d_in[9];
    const float* vw  = (const float*)d_in[10];
    const float* vb  = (const float*)d_in[11];
    const float* rw  = (const float*)d_in[12];
    const float* rb  = (const float*)d_in[13];
    float* out = (float*)d_out;

    int* count = (int*)d_ws;
    int* plist = (int*)((char*)d_ws + NM * sizeof(int));

    (void)hipMemsetAsync(count, 0, NM * sizeof(int), stream);
    k_bucket<<<NPTS / 256, 256, 0, stream>>>(pts, count, plist);
    k_mlp<<<NM, 64, 0, stream>>>(pts, vds, w0, b0, w1, b1, fw, fb, sw, sb,
                                 vw, vb, rw, rb, count, plist, out);
}